// Round 1
// baseline (307.170 us; speedup 1.0000x reference)
//
#include <hip/hip_runtime.h>

// NAM: out[b,c] = bias[c] + sum_f Wout[f]^T · relu(W2[f]^T · relu(x[b,f]*W1[f] + b1[f]) + b2[f])
// B=8192, F=256, H1=64, H2=32, C=10. fp32 everywhere (no fp32 MFMA on CDNA4 -> vector ALU).

#define NB 8192
#define NF 256
#define H1 64
#define H2 32
#define NC 10
#define FPG 16                 // features per group
#define NFG (NF / FPG)         // 16 feature groups
#define ROWS_PER_BLOCK 256

__global__ __launch_bounds__(256) void nam_init_out(const float* __restrict__ bias,
                                                    float* __restrict__ out) {
    int i = blockIdx.x * 256 + threadIdx.x;
    if (i < NB * NC) out[i] = bias[i % NC];
}

__global__ __launch_bounds__(256) void nam_main(const float* __restrict__ x,
                                                const float* __restrict__ W1,
                                                const float* __restrict__ b1,
                                                const float* __restrict__ W2,
                                                const float* __restrict__ b2,
                                                const float* __restrict__ Wout,
                                                float* __restrict__ out) {
    const int b  = blockIdx.x * ROWS_PER_BLOCK + threadIdx.x;  // batch row (per thread)
    const int f0 = blockIdx.y * FPG;                           // this block's feature chunk

    float acc[NC];
#pragma unroll
    for (int c = 0; c < NC; ++c) acc[c] = 0.f;

    // Feature loop kept rolled (16 iters) to bound I-cache footprint.
#pragma unroll 1
    for (int ff = 0; ff < FPG; ++ff) {
        const int f = f0 + ff;
        // Wave-uniform weight pointers -> compiler emits scalar (s_load) fetches.
        const float* __restrict__ W1f = W1 + (size_t)f * H1;
        const float* __restrict__ b1f = b1 + (size_t)f * H1;
        const float* __restrict__ W2f = W2 + (size_t)f * H1 * H2;
        const float* __restrict__ b2f = b2 + (size_t)f * H2;
        const float* __restrict__ Wof = Wout + (size_t)f * H2 * NC;

        const float xval = x[(size_t)b * NF + f];  // per-lane, 1KB stride; L1/L2 hit after line fetch

        float h2[H2];
#pragma unroll
        for (int o = 0; o < H2; ++o) h2[o] = b2f[o];

        // h1 in chunks of 16 so all array indexing is compile-time (no scratch).
#pragma unroll 1
        for (int hc = 0; hc < H1; hc += 16) {
            float h1c[16];
#pragma unroll
            for (int hh = 0; hh < 16; ++hh)
                h1c[hh] = fmaxf(fmaf(xval, W1f[hc + hh], b1f[hc + hh]), 0.f);
#pragma unroll
            for (int hh = 0; hh < 16; ++hh) {
#pragma unroll
                for (int o = 0; o < H2; ++o)
                    h2[o] = fmaf(h1c[hh], W2f[(hc + hh) * H2 + o], h2[o]);
            }
        }

        // relu(h2) -> output contributions
#pragma unroll
        for (int o = 0; o < H2; ++o) {
            const float h = fmaxf(h2[o], 0.f);
#pragma unroll
            for (int c = 0; c < NC; ++c)
                acc[c] = fmaf(h, Wof[o * NC + c], acc[c]);
        }
    }

    float* orow = out + (size_t)b * NC;
#pragma unroll
    for (int c = 0; c < NC; ++c) atomicAdd(&orow[c], acc[c]);
}

extern "C" void kernel_launch(void* const* d_in, const int* in_sizes, int n_in,
                              void* d_out, int out_size, void* d_ws, size_t ws_size,
                              hipStream_t stream) {
    const float* x    = (const float*)d_in[0];
    const float* W1   = (const float*)d_in[1];
    const float* b1   = (const float*)d_in[2];
    const float* W2   = (const float*)d_in[3];
    const float* b2   = (const float*)d_in[4];
    const float* Wout = (const float*)d_in[5];
    const float* bias = (const float*)d_in[6];
    float* out = (float*)d_out;

    // out is poisoned before every call: initialize to bias, then atomically accumulate.
    nam_init_out<<<(NB * NC + 255) / 256, 256, 0, stream>>>(bias, out);

    dim3 grid(NB / ROWS_PER_BLOCK, NFG);  // 32 x 16 = 512 blocks
    nam_main<<<grid, 256, 0, stream>>>(x, W1, b1, W2, b2, Wout, out);
}